// Round 6
// baseline (84.713 us; speedup 1.0000x reference)
//
#include <hip/hip_runtime.h>
#include <math.h>

#define LOG2E 1.4426950408889634f
#define LN2   0.6931471805599453f

typedef float v2f __attribute__((ext_vector_type(2)));

// Params layout: pairwise-AoS. For component pair p = (2p, 2p+1), record of
// 12 floats at pp[12p]: [A0,A1, B0,B1, C0,C1, D0,D1, E0,E1, K0,K1].
// Coefficients pre-scaled by LOG2E and pre-negated (except K):
//   e2 = K + A*xx + B*xy + C*yy + D*sx + E*sy   (base-2 exponent)
__global__ __launch_bounds__(1024) void gm_params(
    const float* __restrict__ mu,         // (M,2)
    const float* __restrict__ sigma_log,  // (M,2)
    const float* __restrict__ theta,      // (M,)
    const float* __restrict__ w,          // (M,1)
    float* __restrict__ pp,               // (12*M/2,)
    float* __restrict__ out)
{
    const int j = threadIdx.x;
    const int lane = j & 63;
    const int wid  = j >> 6;

    const float wj = w[j];

    // logsumexp over w (w ~ N(0,1): raw exp is safe)
    float e = __expf(wj);
    #pragma unroll
    for (int off = 32; off > 0; off >>= 1)
        e += __shfl_down(e, off, 64);

    __shared__ float ws[16];
    if (lane == 0) ws[wid] = e;
    __syncthreads();

    float tot = 0.0f;
    #pragma unroll
    for (int k = 0; k < 16; ++k) tot += ws[k];
    const float lse = __logf(tot);

    const float sl0 = sigma_log[2 * j + 0];
    const float sl1 = sigma_log[2 * j + 1];
    const float a = __expf(-2.0f * sl0);
    const float b = __expf(-2.0f * sl1);
    const float th = theta[j];
    const float c = __cosf(th);
    const float s = __sinf(th);

    const float g11 = a * c * c + b * s * s;
    const float g12 = (a - b) * c * s;
    const float g22 = a * s * s + b * c * c;

    const float mx = mu[2 * j + 0];
    const float my = mu[2 * j + 1];

    const float wlog = wj - lse - (sl0 + sl1);

    const float A = g11;
    const float B = 2.0f * g12;
    const float C = g22;
    const float D = -(2.0f * g11 * mx + 2.0f * g12 * my);
    const float E = -(2.0f * g12 * mx + 2.0f * g22 * my);
    const float F = g11 * mx * mx + 2.0f * g12 * mx * my + g22 * my * my;
    const float K = (wlog - F) * LOG2E;

    const int base = 12 * (j >> 1) + (j & 1);
    pp[base + 0]  = -A * LOG2E;
    pp[base + 2]  = -B * LOG2E;
    pp[base + 4]  = -C * LOG2E;
    pp[base + 6]  = -E * 0.0f - B * 0.0f - D * LOG2E; // = -D*LOG2E (keep simple)
    pp[base + 8]  = -E * LOG2E;
    pp[base + 10] = K;

    if (j == 0) out[0] = 0.0f;
}

// Kernel B: block = 512 = 8 wave-uniform M-chunks; each wave covers 128
// samples (2 per lane, stride 64) x 128 components. Params via scalar s_load
// (wave-uniform), math via packed fp32 (v_pk_fma_f32), 2 samples share each
// param fetch.
__global__ __launch_bounds__(512) void gm_main(
    const float* __restrict__ sample,   // (N,2)
    const float* __restrict__ pp,       // pairwise param records
    float* __restrict__ out,
    int M)
{
    const int lane = threadIdx.x & 63;
    int chunk = __builtin_amdgcn_readfirstlane((int)(threadIdx.x >> 6)); // 0..7
    chunk &= 7;
    __builtin_assume(chunk >= 0 && chunk < 8);

    const int i0 = blockIdx.x * 128 + lane;
    const int i1 = i0 + 64;

    const float2 sv0 = ((const float2*)sample)[i0];
    const float2 sv1 = ((const float2*)sample)[i1];

    const v2f xxA = (v2f)(sv0.x * sv0.x), xxB = (v2f)(sv1.x * sv1.x);
    const v2f xyA = (v2f)(sv0.x * sv0.y), xyB = (v2f)(sv1.x * sv1.y);
    const v2f yyA = (v2f)(sv0.y * sv0.y), yyB = (v2f)(sv1.y * sv1.y);
    const v2f sxA = (v2f)(sv0.x),         sxB = (v2f)(sv1.x);
    const v2f syA = (v2f)(sv0.y),         syB = (v2f)(sv1.y);

    const int pairs = M >> 4;              // 64 pairs per wave chunk
    const v2f* __restrict__ rec = (const v2f*)(pp + 12 * (chunk * pairs));

    v2f accA[2], accB[2];
    accA[0] = accA[1] = accB[0] = accB[1] = (v2f)(0.0f);

    for (int p = 0; p < pairs; p += 4) {
        #pragma unroll
        for (int u = 0; u < 4; ++u) {
            const v2f* r = rec + 6 * (p + u);
            const v2f ra = r[0], rb = r[1], rc = r[2];
            const v2f rd = r[3], re = r[4], rk = r[5];

            v2f eA = rk;
            eA = __builtin_elementwise_fma(ra, xxA, eA);
            eA = __builtin_elementwise_fma(rb, xyA, eA);
            eA = __builtin_elementwise_fma(rc, yyA, eA);
            eA = __builtin_elementwise_fma(rd, sxA, eA);
            eA = __builtin_elementwise_fma(re, syA, eA);

            v2f eB = rk;
            eB = __builtin_elementwise_fma(ra, xxB, eB);
            eB = __builtin_elementwise_fma(rb, xyB, eB);
            eB = __builtin_elementwise_fma(rc, yyB, eB);
            eB = __builtin_elementwise_fma(rd, sxB, eB);
            eB = __builtin_elementwise_fma(re, syB, eB);

            v2f exA, exB;
            exA.x = __builtin_amdgcn_exp2f(eA.x);
            exA.y = __builtin_amdgcn_exp2f(eA.y);
            exB.x = __builtin_amdgcn_exp2f(eB.x);
            exB.y = __builtin_amdgcn_exp2f(eB.y);
            accA[u & 1] += exA;
            accB[u & 1] += exB;
        }
    }

    const v2f avA = accA[0] + accA[1];
    const v2f avB = accB[0] + accB[1];

    __shared__ float psum[8][128];
    psum[chunk][lane]      = avA.x + avA.y;
    psum[chunk][lane + 64] = avB.x + avB.y;
    __syncthreads();

    if (threadIdx.x < 128) {
        const int s = threadIdx.x;
        const float tot = ((psum[0][s] + psum[1][s]) + (psum[2][s] + psum[3][s]))
                        + ((psum[4][s] + psum[5][s]) + (psum[6][s] + psum[7][s]));
        float v = -LN2 * __builtin_amdgcn_logf(tot);
        #pragma unroll
        for (int off = 32; off > 0; off >>= 1)
            v += __shfl_down(v, off, 64);
        if ((s & 63) == 0) atomicAdd(out, v);
    }
}

extern "C" void kernel_launch(void* const* d_in, const int* in_sizes, int n_in,
                              void* d_out, int out_size, void* d_ws, size_t ws_size,
                              hipStream_t stream) {
    const float* sample    = (const float*)d_in[0];
    const float* mu        = (const float*)d_in[1];
    const float* sigma_log = (const float*)d_in[2];
    const float* theta     = (const float*)d_in[3];
    const float* w         = (const float*)d_in[4];
    float* out = (float*)d_out;
    float* pp = (float*)d_ws;

    const int M = in_sizes[3];      // 1024
    const int N = in_sizes[0] / 2;  // 65536

    gm_params<<<1, M, 0, stream>>>(mu, sigma_log, theta, w, pp, out);

    const int grid = N / 128;       // 512 blocks, 512 threads each
    gm_main<<<grid, 512, 0, stream>>>(sample, pp, out, M);
}

// Round 7
// 81.576 us; speedup vs baseline: 1.0385x; 1.0385x over previous
//
#include <hip/hip_runtime.h>
#include <math.h>

#define LOG2E 1.4426950408889634f
#define LN2   0.6931471805599453f

typedef float v2f __attribute__((ext_vector_type(2)));

// Params layout: pairwise-AoS. For component pair p = (2p, 2p+1), record of
// 12 floats at pp[12p]: [A0,A1, B0,B1, C0,C1, D0,D1, E0,E1, K0,K1].
// Coefficients pre-scaled by LOG2E and pre-negated (except K):
//   e2 = K + A*xx + B*xy + C*yy + D*sx + E*sy   (base-2 exponent)
__global__ __launch_bounds__(1024) void gm_params(
    const float* __restrict__ mu,         // (M,2)
    const float* __restrict__ sigma_log,  // (M,2)
    const float* __restrict__ theta,      // (M,)
    const float* __restrict__ w,          // (M,1)
    float* __restrict__ pp,               // (12*M/2,)
    float* __restrict__ out)
{
    const int j = threadIdx.x;
    const int lane = j & 63;
    const int wid  = j >> 6;

    const float wj = w[j];

    // logsumexp over w (w ~ N(0,1): raw exp is safe)
    float e = __expf(wj);
    #pragma unroll
    for (int off = 32; off > 0; off >>= 1)
        e += __shfl_down(e, off, 64);

    __shared__ float ws[16];
    if (lane == 0) ws[wid] = e;
    __syncthreads();

    float tot = 0.0f;
    #pragma unroll
    for (int k = 0; k < 16; ++k) tot += ws[k];
    const float lse = __logf(tot);

    const float sl0 = sigma_log[2 * j + 0];
    const float sl1 = sigma_log[2 * j + 1];
    const float a = __expf(-2.0f * sl0);
    const float b = __expf(-2.0f * sl1);
    const float th = theta[j];
    const float c = __cosf(th);
    const float s = __sinf(th);

    const float g11 = a * c * c + b * s * s;
    const float g12 = (a - b) * c * s;
    const float g22 = a * s * s + b * c * c;

    const float mx = mu[2 * j + 0];
    const float my = mu[2 * j + 1];

    const float wlog = wj - lse - (sl0 + sl1);

    const float A = g11;
    const float B = 2.0f * g12;
    const float C = g22;
    const float D = -(2.0f * g11 * mx + 2.0f * g12 * my);
    const float E = -(2.0f * g12 * mx + 2.0f * g22 * my);
    const float F = g11 * mx * mx + 2.0f * g12 * mx * my + g22 * my * my;
    const float K = (wlog - F) * LOG2E;

    const int base = 12 * (j >> 1) + (j & 1);
    pp[base + 0]  = -A * LOG2E;
    pp[base + 2]  = -B * LOG2E;
    pp[base + 4]  = -C * LOG2E;
    pp[base + 6]  = -D * LOG2E;
    pp[base + 8]  = -E * LOG2E;
    pp[base + 10] = K;

    if (j == 0) out[0] = 0.0f;
}

// Kernel B: block = 1024 threads = 16 wave-uniform M-chunks of 64 components;
// 64 samples per block (1 per lane). 16384 waves total for max TLP.
// Params via scalar s_load (wave-uniform index), math via packed fp32.
__global__ __launch_bounds__(1024) void gm_main(
    const float* __restrict__ sample,   // (N,2)
    const float* __restrict__ pp,       // pairwise param records
    float* __restrict__ out,
    int M)
{
    const int lane = threadIdx.x & 63;     // sample within block
    int chunk = __builtin_amdgcn_readfirstlane((int)(threadIdx.x >> 6)); // 0..15
    chunk &= 15;
    __builtin_assume(chunk >= 0 && chunk < 16);

    const int i = blockIdx.x * 64 + lane;

    const float2 sv = ((const float2*)sample)[i];
    const float sx = sv.x, sy = sv.y;
    const v2f xx2 = (v2f)(sx * sx);
    const v2f xy2 = (v2f)(sx * sy);
    const v2f yy2 = (v2f)(sy * sy);
    const v2f sx2 = (v2f)(sx);
    const v2f sy2 = (v2f)(sy);

    const int pairs = M >> 5;              // 32 pairs (64 comps) per chunk
    const v2f* __restrict__ rec = (const v2f*)(pp + 12 * (chunk * pairs));

    v2f acc[4];
    #pragma unroll
    for (int u = 0; u < 4; ++u) acc[u] = (v2f)(0.0f);

    for (int p = 0; p < pairs; p += 4) {
        #pragma unroll
        for (int u = 0; u < 4; ++u) {
            const v2f* r = rec + 6 * (p + u);
            v2f e = r[5];
            e = __builtin_elementwise_fma(r[0], xx2, e);
            e = __builtin_elementwise_fma(r[1], xy2, e);
            e = __builtin_elementwise_fma(r[2], yy2, e);
            e = __builtin_elementwise_fma(r[3], sx2, e);
            e = __builtin_elementwise_fma(r[4], sy2, e);
            v2f ex;
            ex.x = __builtin_amdgcn_exp2f(e.x);
            ex.y = __builtin_amdgcn_exp2f(e.y);
            acc[u] += ex;
        }
    }

    const v2f accv = (acc[0] + acc[1]) + (acc[2] + acc[3]);

    __shared__ float psum[16][64];
    psum[chunk][lane] = accv.x + accv.y;
    __syncthreads();

    if (threadIdx.x < 64) {
        const int s = threadIdx.x;
        float tot = 0.0f;
        #pragma unroll
        for (int k = 0; k < 16; ++k) tot += psum[k][s];
        float v = -LN2 * __builtin_amdgcn_logf(tot);
        #pragma unroll
        for (int off = 32; off > 0; off >>= 1)
            v += __shfl_down(v, off, 64);
        if (s == 0) atomicAdd(out, v);
    }
}

extern "C" void kernel_launch(void* const* d_in, const int* in_sizes, int n_in,
                              void* d_out, int out_size, void* d_ws, size_t ws_size,
                              hipStream_t stream) {
    const float* sample    = (const float*)d_in[0];
    const float* mu        = (const float*)d_in[1];
    const float* sigma_log = (const float*)d_in[2];
    const float* theta     = (const float*)d_in[3];
    const float* w         = (const float*)d_in[4];
    float* out = (float*)d_out;
    float* pp = (float*)d_ws;

    const int M = in_sizes[3];      // 1024
    const int N = in_sizes[0] / 2;  // 65536

    gm_params<<<1, M, 0, stream>>>(mu, sigma_log, theta, w, pp, out);

    const int grid = N / 64;        // 1024 blocks, 1024 threads each
    gm_main<<<grid, 1024, 0, stream>>>(sample, pp, out, M);
}

// Round 8
// 80.350 us; speedup vs baseline: 1.0543x; 1.0153x over previous
//
#include <hip/hip_runtime.h>
#include <math.h>

#define LOG2E 1.4426950408889634f
#define LN2   0.6931471805599453f

typedef float v2f __attribute__((ext_vector_type(2)));

// Fully fused kernel. Block = 1024 threads = 16 waves.
// Phase 1-2: each block redundantly computes all M component coefficient
//   records into LDS (1 comp/thread), incl. block-local logsumexp over w.
//   Record for pair p (comps 2p,2p+1), 12 floats at lds offset 12p:
//   [A0,A1, B0,B1, C0,C1, D0,D1, E0,E1, K0,K1], pre-scaled by LOG2E,
//   pre-negated (except K):  e2 = K + A*xx + B*xy + C*yy + D*sx + E*sy
// Phase 3: wave w handles samples blockIdx*64+lane over comp chunk w
//   (64 comps = 32 pairs), records read via broadcast ds_read_b128.
// Phase 4: LDS combine across 16 chunks, log, wave-reduce, 1 atomic/block.
__global__ __launch_bounds__(1024) void gm_fused(
    const float* __restrict__ sample,     // (N,2)
    const float* __restrict__ mu,         // (M,2)
    const float* __restrict__ sigma_log,  // (M,2)
    const float* __restrict__ theta,      // (M,)
    const float* __restrict__ w,          // (M,1)
    float* __restrict__ out,
    int M)
{
    __shared__ float4 recs4[512 * 3];     // 24 KB: M/2 pair records
    __shared__ float  ws[16];
    __shared__ float  psum[16][64];

    const int tid  = threadIdx.x;
    const int lane = tid & 63;
    const int wid  = tid >> 6;            // 0..15

    // Issue the sample load early (used in phase 3).
    const int i = blockIdx.x * 64 + lane;
    const float2 sv = ((const float2*)sample)[i];

    // ---- Phase 1: block logsumexp over w (all M=1024 values, 1/thread) ----
    const float wj = w[tid];
    float e = __expf(wj);                 // w ~ N(0,1): raw exp safe
    #pragma unroll
    for (int off = 32; off > 0; off >>= 1)
        e += __shfl_down(e, off, 64);
    if (lane == 0) ws[wid] = e;
    __syncthreads();
    float tot = 0.0f;
    #pragma unroll
    for (int k = 0; k < 16; ++k) tot += ws[k];
    const float lse = __logf(tot);

    // ---- Phase 2: coefficients for component tid -> LDS record ----
    {
        const float sl0 = sigma_log[2 * tid + 0];
        const float sl1 = sigma_log[2 * tid + 1];
        const float a = __expf(-2.0f * sl0);
        const float b = __expf(-2.0f * sl1);
        const float th = theta[tid];
        const float c = __cosf(th);
        const float s = __sinf(th);

        const float g11 = a * c * c + b * s * s;
        const float g12 = (a - b) * c * s;
        const float g22 = a * s * s + b * c * c;

        const float mx = mu[2 * tid + 0];
        const float my = mu[2 * tid + 1];

        const float wlog = wj - lse - (sl0 + sl1);

        const float A = g11;
        const float B = 2.0f * g12;
        const float C = g22;
        const float D = -(2.0f * g11 * mx + 2.0f * g12 * my);
        const float E = -(2.0f * g12 * mx + 2.0f * g22 * my);
        const float F = g11 * mx * mx + 2.0f * g12 * mx * my + g22 * my * my;
        const float K = (wlog - F) * LOG2E;

        float* recs = (float*)recs4;
        const int base = 12 * (tid >> 1) + (tid & 1);
        recs[base + 0]  = -A * LOG2E;
        recs[base + 2]  = -B * LOG2E;
        recs[base + 4]  = -C * LOG2E;
        recs[base + 6]  = -D * LOG2E;
        recs[base + 8]  = -E * LOG2E;
        recs[base + 10] = K;
    }
    __syncthreads();

    // ---- Phase 3: main loop over this wave's 32 pair-records ----
    const float sx = sv.x, sy = sv.y;
    const v2f xx2 = (v2f)(sx * sx);
    const v2f xy2 = (v2f)(sx * sy);
    const v2f yy2 = (v2f)(sy * sy);
    const v2f sx2 = (v2f)(sx);
    const v2f sy2 = (v2f)(sy);

    const int pairs = M >> 5;             // 32 pairs per chunk
    const int p0 = wid * pairs;           // wave-uniform

    v2f acc[4];
    #pragma unroll
    for (int u = 0; u < 4; ++u) acc[u] = (v2f)(0.0f);

    for (int p = 0; p < pairs; p += 4) {
        #pragma unroll
        for (int u = 0; u < 4; ++u) {
            const float4* r4 = &recs4[3 * (p0 + p + u)];
            const float4 r0 = r4[0];      // A0 A1 B0 B1
            const float4 r1 = r4[1];      // C0 C1 D0 D1
            const float4 r2 = r4[2];      // E0 E1 K0 K1
            const v2f ra = {r0.x, r0.y};
            const v2f rb = {r0.z, r0.w};
            const v2f rc = {r1.x, r1.y};
            const v2f rd = {r1.z, r1.w};
            const v2f re = {r2.x, r2.y};
            const v2f rk = {r2.z, r2.w};

            v2f ev = rk;
            ev = __builtin_elementwise_fma(ra, xx2, ev);
            ev = __builtin_elementwise_fma(rb, xy2, ev);
            ev = __builtin_elementwise_fma(rc, yy2, ev);
            ev = __builtin_elementwise_fma(rd, sx2, ev);
            ev = __builtin_elementwise_fma(re, sy2, ev);

            v2f ex;
            ex.x = __builtin_amdgcn_exp2f(ev.x);
            ex.y = __builtin_amdgcn_exp2f(ev.y);
            acc[u] += ex;
        }
    }

    const v2f accv = (acc[0] + acc[1]) + (acc[2] + acc[3]);
    psum[wid][lane] = accv.x + accv.y;
    __syncthreads();

    // ---- Phase 4: combine chunks, log, reduce, atomic ----
    if (tid < 64) {
        float t = 0.0f;
        #pragma unroll
        for (int k = 0; k < 16; ++k) t += psum[k][tid];
        float v = -LN2 * __builtin_amdgcn_logf(t);
        #pragma unroll
        for (int off = 32; off > 0; off >>= 1)
            v += __shfl_down(v, off, 64);
        if (tid == 0) atomicAdd(out, v);
    }
}

extern "C" void kernel_launch(void* const* d_in, const int* in_sizes, int n_in,
                              void* d_out, int out_size, void* d_ws, size_t ws_size,
                              hipStream_t stream) {
    const float* sample    = (const float*)d_in[0];
    const float* mu        = (const float*)d_in[1];
    const float* sigma_log = (const float*)d_in[2];
    const float* theta     = (const float*)d_in[3];
    const float* w         = (const float*)d_in[4];
    float* out = (float*)d_out;

    const int M = in_sizes[3];      // 1024
    const int N = in_sizes[0] / 2;  // 65536

    // Zero the accumulator (harness poisons d_out before every launch).
    hipMemsetAsync(out, 0, sizeof(float), stream);

    const int grid = N / 64;        // 1024 blocks, 1024 threads each
    gm_fused<<<grid, 1024, 0, stream>>>(sample, mu, sigma_log, theta, w, out, M);
}